// Round 4
// baseline (121.381 us; speedup 1.0000x reference)
//
#include <hip/hip_runtime.h>
#include <stdint.h>

typedef float f4_t __attribute__((ext_vector_type(4)));
typedef __bf16 bf8_t __attribute__((ext_vector_type(8)));
typedef unsigned short us4_t __attribute__((ext_vector_type(4)));
typedef unsigned short us8_t __attribute__((ext_vector_type(8)));

static __device__ __forceinline__ unsigned short fbf(float f) {
    __bf16 b = (__bf16)f;
    return *(unsigned short*)&b;
}
static __device__ __forceinline__ float bf2f(unsigned short u) {
    union { uint32_t u; float f; } v; v.u = ((uint32_t)u) << 16;
    return v.f;
}
static __device__ __forceinline__ f4_t mfma16(bf8_t a, bf8_t b, f4_t c) {
    return __builtin_amdgcn_mfma_f32_16x16x32_bf16(a, b, c, 0, 0, 0);
}
static __device__ __forceinline__ float sigf(float x) {
    return 1.0f / (1.0f + __expf(-x));
}

// ---------------- kernel 0: convert x/h/W to bf16, build q-normalized x ----
__global__ __launch_bounds__(256) void k_convert(
    const float* __restrict__ x, const float* __restrict__ h,
    const float* __restrict__ W1, const float* __restrict__ W2,
    unsigned short* __restrict__ qn, unsigned short* __restrict__ xb,
    unsigned short* __restrict__ hb, unsigned short* __restrict__ w1b,
    unsigned short* __restrict__ w2b)
{
    __shared__ float sred[4];
    int bid = blockIdx.x, t = threadIdx.x;
    if (bid < 256) {
        float v = x[bid * 256 + t];
        float ss = v * v;
        #pragma unroll
        for (int m = 1; m < 64; m <<= 1) ss += __shfl_xor(ss, m, 64);
        if ((t & 63) == 0) sred[t >> 6] = ss;
        __syncthreads();
        float tot = sred[0] + sred[1] + sred[2] + sred[3];
        float rn = 1.0f / fmaxf(sqrtf(tot), 1e-8f);
        xb[bid * 256 + t] = fbf(v);
        qn[bid * 256 + t] = fbf(v * rn);
    } else if (bid < 512) {
        int b = bid - 256;
        hb[b * 256 + t] = fbf(h[b * 256 + t]);
    } else {
        int i0 = (bid - 512) * 256 + t;
        for (int i = i0; i < 1280 * 256; i += 512 * 256) {
            w1b[i] = fbf(W1[i]);
            w2b[i] = fbf(W2[i]);
        }
    }
}

// ---------------- kernel 1: preact = x@W1^T + h@W2^T + b1 + b2 --------------
__global__ __launch_bounds__(256) void k_gates(
    const unsigned short* __restrict__ xb, const unsigned short* __restrict__ hb,
    const unsigned short* __restrict__ w1b, const unsigned short* __restrict__ w2b,
    const float* __restrict__ b1, const float* __restrict__ b2,
    float* __restrict__ pre)
{
    int bb = (blockIdx.x & 3) * 64;
    int gb = (blockIdx.x >> 2) * 64;
    int t = threadIdx.x, w = t >> 6, lane = t & 63;
    int l15 = lane & 15, q8 = (lane >> 4) * 8, q4 = (lane >> 4) * 4;
    int arow = bb + w * 16 + l15;

    f4_t acc[4] = {};
    #pragma unroll
    for (int ks = 0; ks < 8; ++ks) {
        bf8_t a = *(const bf8_t*)&xb[arow * 256 + ks * 32 + q8];
        #pragma unroll
        for (int gc = 0; gc < 4; ++gc) {
            bf8_t bf = *(const bf8_t*)&w1b[(gb + gc * 16 + l15) * 256 + ks * 32 + q8];
            acc[gc] = mfma16(a, bf, acc[gc]);
        }
    }
    #pragma unroll
    for (int ks = 0; ks < 8; ++ks) {
        bf8_t a = *(const bf8_t*)&hb[arow * 256 + ks * 32 + q8];
        #pragma unroll
        for (int gc = 0; gc < 4; ++gc) {
            bf8_t bf = *(const bf8_t*)&w2b[(gb + gc * 16 + l15) * 256 + ks * 32 + q8];
            acc[gc] = mfma16(a, bf, acc[gc]);
        }
    }
    #pragma unroll
    for (int gc = 0; gc < 4; ++gc) {
        int g = gb + gc * 16 + l15;
        float bias = b1[g] + b2[g];
        #pragma unroll
        for (int r = 0; r < 4; ++r) {
            int b = bb + w * 16 + q4 + r;
            pre[b * 1280 + g] = acc[gc][r] + bias;
        }
    }
}

// ---------------- kernel 2: fused DND memory partials ------------------------
// 256 blocks = 128 chunks x 2 b-halves (twins bid/bid^8 on same XCD share
// K/V tiles via L2). 512 threads, 8 waves; wave w owns b-rows w*16..+15.
// Reads raw fp32 keys+vals; reg-stage, K-normalize in-register, bf16-convert,
// conflict-minimal swizzled LDS writes; double-buffered, ONE barrier/tile.
__global__ __launch_bounds__(512, 2) void k_dnd(
    const float* __restrict__ keys, const float* __restrict__ vals,
    const unsigned short* __restrict__ qn,
    unsigned short* __restrict__ opart, float* __restrict__ dpart,
    int L, int CH)
{
    // K0 @0 | K1 @32768 | V0 @65536 | V1 @98304 | P @131072  (total 144KB)
    __shared__ __align__(16) char smem[147456];
    unsigned short* Pl = (unsigned short*)(smem + 131072);

    const int t = threadIdx.x;
    const int w = t >> 6;
    const int lane = t & 63;
    const int l15 = lane & 15;
    const int q8 = (lane >> 4) * 8;
    const int q4 = (lane >> 4) * 4;

    const int bid = blockIdx.x;
    const int bhalf = (bid >> 3) & 1;
    const int chunk = (bid & 7) | ((bid >> 4) << 3);
    const int base = chunk * CH;
    int nkeys = L - base;
    if (nkeys > CH) nkeys = CH;
    if (nkeys < 0) nkeys = 0;
    const int nt = (nkeys + 63) >> 6;

    // K staging map: thread covers row kr, 32 float cols at kc
    const int kr = t >> 3;
    const int kc = (t & 7) * 32;
    // V staging map: thread covers h-quad vm (h=4vm..+3), l-octet vlw*8..+7
    const int vm = t & 63;
    const int vlw = t >> 6;

    // Q fragments (L2-resident bf16)
    bf8_t qa[8];
    #pragma unroll
    for (int ks = 0; ks < 8; ++ks)
        qa[ks] = *(const bf8_t*)&qn[(bhalf * 128 + w * 16 + l15) * 256 + ks * 32 + q8];

    f4_t o[16] = {};
    float den[4] = {};
    f4_t kst[8], vst[8];

    auto issueK = [&](int tt) {
        int row = base + tt * 64 + kr;
        row = min(row, L - 1);
        const float* src = keys + (size_t)row * 256 + kc;
        #pragma unroll
        for (int i = 0; i < 8; ++i) kst[i] = *(const f4_t*)(src + 4 * i);
    };
    auto issueV = [&](int tt) {
        #pragma unroll
        for (int r = 0; r < 8; ++r) {
            int row = base + tt * 64 + vlw * 8 + r;
            row = min(row, L - 1);
            vst[r] = *(const f4_t*)&vals[(size_t)row * 256 + vm * 4];
        }
    };
    auto writeK = [&](char* kb) {
        float ss = 0.f;
        #pragma unroll
        for (int i = 0; i < 8; ++i)
            ss += kst[i][0]*kst[i][0] + kst[i][1]*kst[i][1]
                + kst[i][2]*kst[i][2] + kst[i][3]*kst[i][3];
        ss += __shfl_xor(ss, 1, 64);
        ss += __shfl_xor(ss, 2, 64);
        ss += __shfl_xor(ss, 4, 64);
        float rn = 1.0f / fmaxf(sqrtf(ss), 1e-8f);
        unsigned short* K = (unsigned short*)kb;
        #pragma unroll
        for (int jj = 0; jj < 4; ++jj) {
            us8_t uv;
            #pragma unroll
            for (int d = 0; d < 4; ++d) {
                uv[d]     = fbf(kst[jj*2][d] * rn);
                uv[d + 4] = fbf(kst[jj*2 + 1][d] * rn);
            }
            *(us8_t*)&K[kr * 256 + ((kc + 8*jj) ^ ((kr & 7) * 8))] = uv;
        }
    };
    auto writeV = [&](char* vb) {
        unsigned short* V = (unsigned short*)vb;
        #pragma unroll
        for (int j = 0; j < 4; ++j) {
            int hh = vm * 4 + j;
            int g = (vm ^ (j << 1)) & 7;
            us8_t uv;
            #pragma unroll
            for (int r = 0; r < 8; ++r) uv[r] = fbf(vst[r][j]);
            *(us8_t*)&V[hh * 64 + ((vlw * 8) ^ (g * 8))] = uv;
        }
    };

    if (nt > 0) {
        issueK(0); issueV(0);
        asm volatile("s_waitcnt vmcnt(0)" ::: "memory");
        writeK(smem); writeV(smem + 65536);
        if (nt > 1) { issueK(1); issueV(1); }
        asm volatile("s_waitcnt lgkmcnt(0)\n\ts_barrier" ::: "memory");

        for (int tt = 0; tt < nt; ++tt) {
            const int cur = tt & 1;
            const unsigned short* Kl = (const unsigned short*)(smem + cur * 32768);
            const unsigned short* Vl = (const unsigned short*)(smem + 65536 + cur * 32768);

            // ---- GEMM1: S = Q @ Kn^T (wave: 16 b x 64 l) ----
            f4_t s[4] = {};
            __builtin_amdgcn_s_setprio(1);
            #pragma unroll
            for (int lc = 0; lc < 4; ++lc) {
                int l = lc * 16 + l15;
                int sw = (l & 7) * 8;
                #pragma unroll
                for (int ks = 0; ks < 8; ++ks) {
                    bf8_t kf = *(const bf8_t*)&Kl[l * 256 + ((ks * 32 + q8) ^ sw)];
                    s[lc] = mfma16(qa[ks], kf, s[lc]);
                }
            }
            __builtin_amdgcn_s_setprio(0);

            // ---- p = exp(s - 1) (sims in [-1,1]); den; P -> LDS ----
            #pragma unroll
            for (int lc = 0; lc < 4; ++lc) {
                int l = lc * 16 + l15;
                bool valid = (tt * 64 + l) < nkeys;
                #pragma unroll
                for (int r = 0; r < 4; ++r) {
                    float p = valid ? __expf(s[lc][r] - 1.0f) : 0.0f;
                    den[r] += p;
                    int br = w * 16 + q4 + r;
                    Pl[br * 64 + (l ^ ((br & 7) * 8))] = fbf(p);
                }
            }

            // ---- GEMM2: O += P @ V ----
            {
                int brow = w * 16 + l15;
                int swp = (brow & 7) * 8;
                bf8_t pa0 = *(const bf8_t*)&Pl[brow * 64 + (q8 ^ swp)];
                bf8_t pa1 = *(const bf8_t*)&Pl[brow * 64 + ((32 + q8) ^ swp)];
                __builtin_amdgcn_s_setprio(1);
                #pragma unroll
                for (int hc = 0; hc < 16; ++hc) {
                    int hh = hc * 16 + l15;
                    int g = ((hh >> 2) ^ ((hh & 3) << 1)) & 7;
                    bf8_t vf0 = *(const bf8_t*)&Vl[hh * 64 + (q8 ^ (g * 8))];
                    bf8_t vf1 = *(const bf8_t*)&Vl[hh * 64 + ((32 + q8) ^ (g * 8))];
                    o[hc] = mfma16(pa0, vf0, o[hc]);
                    o[hc] = mfma16(pa1, vf1, o[hc]);
                }
                __builtin_amdgcn_s_setprio(0);
            }

            // ---- stage tile t+1 into the other buffers ----
            if (tt + 1 < nt) {
                asm volatile("s_waitcnt vmcnt(0)" ::: "memory");
                char* kb = smem + (cur ^ 1) * 32768;
                char* vb = smem + 65536 + (cur ^ 1) * 32768;
                writeK(kb); writeV(vb);
                if (tt + 2 < nt) { issueK(tt + 2); issueV(tt + 2); }
                asm volatile("s_waitcnt lgkmcnt(0)\n\ts_barrier" ::: "memory");
            }
        }
    }

    // ---- epilogue: LDS transpose -> coalesced 16B/lane stores ----
    __syncthreads();
    unsigned short* Ol = (unsigned short*)smem;   // [128 b][256 h]
    #pragma unroll
    for (int hc = 0; hc < 16; ++hc)
        #pragma unroll
        for (int r = 0; r < 4; ++r)
            Ol[(w * 16 + q4 + r) * 256 + hc * 16 + l15] = fbf(o[hc][r]);
    __syncthreads();
    {
        size_t ob = (size_t)(chunk * 2 + bhalf) * 32768;
        #pragma unroll
        for (int it = 0; it < 8; ++it) {
            int off = it * 4096 + t * 8;
            *(us8_t*)&opart[ob + off] = *(const us8_t*)&Ol[off];
        }
    }
    #pragma unroll
    for (int r = 0; r < 4; ++r) {
        float d = den[r];
        #pragma unroll
        for (int m = 1; m < 16; m <<= 1) d += __shfl_xor(d, m, 64);
        if (l15 == 0)
            dpart[chunk * 256 + bhalf * 128 + w * 16 + q4 + r] = d;
    }
}

// ---------------- kernel 3: reduce partials + LSTM epilogue -----------------
__global__ __launch_bounds__(256) void k_reduce(
    const unsigned short* __restrict__ opart, const float* __restrict__ dpart,
    const float* __restrict__ pre, const float* __restrict__ c_in,
    float* __restrict__ out)
{
    __shared__ float sred[4];
    int b = blockIdx.x, t = threadIdx.x;

    float ds = (t < 128) ? dpart[t * 256 + b] : 0.0f;
    #pragma unroll
    for (int m = 1; m < 64; m <<= 1) ds += __shfl_xor(ds, m, 64);
    if ((t & 63) == 0) sred[t >> 6] = ds;
    __syncthreads();
    float dtot = fmaxf(sred[0] + sred[1] + sred[2] + sred[3], 1e-30f);

    int bh = b >> 7, br = b & 127;
    float n0 = 0.f, n1 = 0.f, n2 = 0.f, n3 = 0.f;
    for (int ck = 0; ck < 128; ck += 4) {
        n0 += bf2f(opart[(size_t)((ck + 0) * 2 + bh) * 32768 + br * 256 + t]);
        n1 += bf2f(opart[(size_t)((ck + 1) * 2 + bh) * 32768 + br * 256 + t]);
        n2 += bf2f(opart[(size_t)((ck + 2) * 2 + bh) * 32768 + br * 256 + t]);
        n3 += bf2f(opart[(size_t)((ck + 3) * 2 + bh) * 32768 + br * 256 + t]);
    }
    float num = (n0 + n1) + (n2 + n3);

    float m = tanhf(num / dtot);
    const float* p = pre + b * 1280;
    float fg = sigf(p[t]);
    float ig = sigf(p[256 + t]);
    float og = sigf(p[512 + t]);
    float rg = sigf(p[768 + t]);
    float cn = tanhf(p[1024 + t]);
    float co = c_in[b * 256 + t];
    float ct = fg * co + ig * cn + rg * m;
    float ht = og * tanhf(ct);
    out[b * 256 + t] = ht;
    out[65536 + b * 256 + t] = ct;
}

// ---------------- launch ----------------------------------------------------
extern "C" void kernel_launch(void* const* d_in, const int* in_sizes, int n_in,
                              void* d_out, int out_size, void* d_ws, size_t ws_size,
                              hipStream_t stream)
{
    const float* x    = (const float*)d_in[0];
    const float* h    = (const float*)d_in[1];
    const float* c    = (const float*)d_in[2];
    const float* W1   = (const float*)d_in[3];
    const float* b1   = (const float*)d_in[4];
    const float* W2   = (const float*)d_in[5];
    const float* b2   = (const float*)d_in[6];
    const float* keys = (const float*)d_in[7];
    const float* vals = (const float*)d_in[8];
    int L = in_sizes[7] / 256;

    int TILES = (L + 128 * 64 - 1) / (128 * 64);   // tiles per chunk
    int CH = TILES * 64;                           // keys per chunk

    char* ws = (char*)d_ws;
    unsigned short* qn    = (unsigned short*)(ws + 0);
    unsigned short* xb    = (unsigned short*)(ws + 131072);
    unsigned short* hb    = (unsigned short*)(ws + 262144);
    unsigned short* w1b   = (unsigned short*)(ws + 393216);
    unsigned short* w2b   = (unsigned short*)(ws + 1048576);
    float*          pre   = (float*)(ws + 1703936);
    float*          dpart = (float*)(ws + 3014656);
    unsigned short* opart = (unsigned short*)(ws + 3145728);

    k_convert<<<dim3(1024), dim3(256), 0, stream>>>(x, h, W1, W2, qn, xb, hb, w1b, w2b);
    k_gates<<<dim3(80), dim3(256), 0, stream>>>(xb, hb, w1b, w2b, b1, b2, pre);
    k_dnd<<<dim3(256), dim3(512), 0, stream>>>(keys, vals, qn, opart, dpart, L, CH);
    k_reduce<<<dim3(256), dim3(256), 0, stream>>>(opart, dpart, pre, c, (float*)d_out);

    (void)n_in; (void)out_size; (void)ws_size;
}